// Round 1
// baseline (536.457 us; speedup 1.0000x reference)
//
#include <hip/hip_runtime.h>
#include <hip/hip_cooperative_groups.h>
#include <math.h>

namespace cg = cooperative_groups;

#define H 1024
#define NB 5
#define IN 42
#define C_OUT 1000

__device__ __forceinline__ float sigmoidf_(float x) {
    return 1.0f / (1.0f + expf(-x));
}

__device__ __forceinline__ float wave_reduce_sum(float v) {
    #pragma unroll
    for (int off = 32; off > 0; off >>= 1) v += __shfl_xor(v, off);
    return v;
}

// ---------------------------------------------------------------------------
// Mega kernel: prep + layer0 + layer1 + fuse + fc, 3 grid syncs.
// Grid: 1024 blocks x 256 threads. __launch_bounds__(256,4) -> VGPR<=128 ->
// 4 blocks/CU -> exactly 1024 co-resident blocks on 256 CUs (cooperative-safe).
// ---------------------------------------------------------------------------
__global__ __launch_bounds__(256, 4)
void mega_kernel(const float* __restrict__ x,
                 const float* __restrict__ wih0,
                 const float* __restrict__ bih0,
                 const float* __restrict__ bhh0,
                 const float* __restrict__ wih1,
                 const float* __restrict__ bih1,
                 const float* __restrict__ bhh1,
                 const float* __restrict__ fuse_w,
                 const float* __restrict__ fuse_b,
                 const float* __restrict__ fc_w,
                 const float* __restrict__ fc_b,
                 float* __restrict__ h0,
                 float* __restrict__ ctx,
                 float* __restrict__ fused,
                 float* __restrict__ out) {
    cg::grid_group grid = cg::this_grid();

    __shared__ float slx[21], sly[21], srx[21], sry[21];
    __shared__ float sxb[NB * IN];   // all 5 branch inputs
    __shared__ float sred[4];

    int t = threadIdx.x;
    int wave = t >> 6;
    int lane = t & 63;
    int gw = blockIdx.x * 4 + wave;   // global wave id in [0, 4096)

    // ---------------- phase 0a: prep (redundant per block, tiny) ----------
    if (t < 21) {
        slx[t] = x[(91 + t) * 2 + 0];
        sly[t] = x[(91 + t) * 2 + 1];
        srx[t] = x[(112 + t) * 2 + 0];
        sry[t] = x[(112 + t) * 2 + 1];
    }
    __syncthreads();
    if (t < 21) {
        float lx_min = slx[0], lx_max = slx[0], ly_min = sly[0], ly_max = sly[0];
        float rx_min = srx[0], rx_max = srx[0], ry_min = sry[0], ry_max = sry[0];
        #pragma unroll
        for (int i = 1; i < 21; ++i) {
            lx_min = fminf(lx_min, slx[i]); lx_max = fmaxf(lx_max, slx[i]);
            ly_min = fminf(ly_min, sly[i]); ly_max = fmaxf(ly_max, sly[i]);
            rx_min = fminf(rx_min, srx[i]); rx_max = fmaxf(rx_max, srx[i]);
            ry_min = fminf(ry_min, sry[i]); ry_max = fmaxf(ry_max, sry[i]);
        }
        float w_l = lx_max - lx_min, h_l = ly_max - ly_min;
        float w_r = rx_max - rx_min, h_r = ry_max - ry_min;
        float w_b = x[5 * 2 + 0] - x[6 * 2 + 0];
        float h_b = 4.0f * w_b;
        float sbx = x[0], sby = x[1];
        bool cond_l = (w_l != 0.0f) && (h_l != 0.0f);
        bool cond_r = (w_r != 0.0f) && (h_r != 0.0f);
        bool cond_b = (w_b != 0.0f) && (h_b != 0.0f);
        float dlx = cond_l ? w_l : 1.0f, dly = cond_l ? h_l : 1.0f;
        float drx = cond_r ? w_r : 1.0f, dry = cond_r ? h_r : 1.0f;
        float wb  = cond_b ? w_b : 1.0f, hb  = cond_b ? h_b : 1.0f;

        float lx = slx[t], ly = sly[t], rx = srx[t], ry = sry[t];
        float slx0 = slx[9], sly0 = sly[9], srx0 = srx[9], sry0 = sry[9];
        sxb[0 * IN + 2 * t + 0] = (lx - slx0) / dlx;
        sxb[0 * IN + 2 * t + 1] = (ly - sly0) / dly;
        sxb[1 * IN + 2 * t + 0] = (rx - srx0) / drx;
        sxb[1 * IN + 2 * t + 1] = (ry - sry0) / dry;
        sxb[2 * IN + 2 * t + 0] = (lx - sbx) / wb;
        sxb[2 * IN + 2 * t + 1] = (ly - sby);
        sxb[3 * IN + 2 * t + 0] = (rx - sbx);
        sxb[3 * IN + 2 * t + 1] = (ry - sby) / hb;
        sxb[4 * IN + 2 * t + 0] = (lx - rx) / wb;
        sxb[4 * IN + 2 * t + 1] = (ly - ry) / hb;
    }
    __syncthreads();

    // ---------------- phase 0b: layer0 LSTM (h=c=0, f-gate dead) ----------
    #pragma unroll
    for (int rep = 0; rep < 2; ++rep) {
        int idx = gw + rep * 4096;
        if (idx < NB * H) {
            int b = idx >> 10;
            int j = idx & (H - 1);
            const float* Wb = wih0 + (size_t)b * 4 * H * IN;
            float gi = 0.0f, gg = 0.0f, go = 0.0f;
            if (lane < IN) {
                float xv = sxb[b * IN + lane];
                gi = Wb[(size_t)(j)         * IN + lane] * xv;
                gg = Wb[(size_t)(j + 2 * H) * IN + lane] * xv;
                go = Wb[(size_t)(j + 3 * H) * IN + lane] * xv;
            }
            gi = wave_reduce_sum(gi);
            gg = wave_reduce_sum(gg);
            go = wave_reduce_sum(go);
            if (lane == 0) {
                size_t base = (size_t)b * 4 * H;
                gi += bih0[base + j]         + bhh0[base + j];
                gg += bih0[base + j + 2 * H] + bhh0[base + j + 2 * H];
                go += bih0[base + j + 3 * H] + bhh0[base + j + 3 * H];
                float c2 = sigmoidf_(gi) * tanhf(gg);
                h0[idx] = sigmoidf_(go) * tanhf(c2);
            }
        }
    }
    grid.sync();

    // ---------------- phase 1: layer1 LSTM (h=c=0) ------------------------
    #pragma unroll
    for (int rep = 0; rep < 2; ++rep) {
        int idx = gw + rep * 4096;
        if (idx < NB * H) {
            int b = idx >> 10;
            int j = idx & (H - 1);
            const float4* hb4 = (const float4*)(h0 + (size_t)b * H);
            const float* Wb = wih1 + (size_t)b * 4 * H * H;
            const float4* ri = (const float4*)(Wb + (size_t)(j)         * H);
            const float4* rg = (const float4*)(Wb + (size_t)(j + 2 * H) * H);
            const float4* ro = (const float4*)(Wb + (size_t)(j + 3 * H) * H);
            float gi = 0.0f, gg = 0.0f, go = 0.0f;
            #pragma unroll
            for (int r = 0; r < 4; ++r) {
                int k = lane + 64 * r;
                float4 h4 = hb4[k];
                float4 a = ri[k]; gi += a.x * h4.x + a.y * h4.y + a.z * h4.z + a.w * h4.w;
                float4 c = rg[k]; gg += c.x * h4.x + c.y * h4.y + c.z * h4.z + c.w * h4.w;
                float4 d = ro[k]; go += d.x * h4.x + d.y * h4.y + d.z * h4.z + d.w * h4.w;
            }
            gi = wave_reduce_sum(gi);
            gg = wave_reduce_sum(gg);
            go = wave_reduce_sum(go);
            if (lane == 0) {
                size_t base = (size_t)b * 4 * H;
                gi += bih1[base + j]         + bhh1[base + j];
                gg += bih1[base + j + 2 * H] + bhh1[base + j + 2 * H];
                go += bih1[base + j + 3 * H] + bhh1[base + j + 3 * H];
                float c2 = sigmoidf_(gi) * tanhf(gg);
                ctx[idx] = sigmoidf_(go) * tanhf(c2);   // softmax over 1 elem == 1
            }
        }
    }
    grid.sync();

    // ---------------- phase 2: fused = fuse_w @ ctx + fuse_b --------------
    {
        int row = blockIdx.x;   // 1024 blocks <-> 1024 rows, exact
        const float4* r4 = (const float4*)(fuse_w + (size_t)row * (NB * H));
        const float4* c4 = (const float4*)ctx;
        float acc = 0.0f;
        #pragma unroll
        for (int k = t; k < (NB * H) / 4; k += 256) {   // 5 iters
            float4 a = r4[k], c = c4[k];
            acc += a.x * c.x + a.y * c.y + a.z * c.z + a.w * c.w;
        }
        acc = wave_reduce_sum(acc);
        if (lane == 0) sred[wave] = acc;
        __syncthreads();
        if (t == 0) fused[row] = sred[0] + sred[1] + sred[2] + sred[3] + fuse_b[row];
    }
    grid.sync();

    // ---------------- phase 3: logits = fc_w @ fused + fc_b ---------------
    if (blockIdx.x < C_OUT) {
        int row = blockIdx.x;
        const float4* r4 = (const float4*)(fc_w + (size_t)row * H);
        const float4* f4 = (const float4*)fused;
        float4 a = r4[t];           // 256 threads x float4 = 1024 floats, exact
        float4 f = f4[t];
        float acc = a.x * f.x + a.y * f.y + a.z * f.z + a.w * f.w;
        acc = wave_reduce_sum(acc);
        if (lane == 0) sred[wave] = acc;
        __syncthreads();
        if (t == 0) out[row] = sred[0] + sred[1] + sred[2] + sred[3] + fc_b[row];
    }
}

// ===========================================================================
// Fallback path (non-cooperative): the previous verified 4-kernel pipeline.
// Used only if the cooperative enqueue is rejected at runtime.
// ===========================================================================
__global__ void layer0_kernel(const float* __restrict__ x,
                              const float* __restrict__ wih0,
                              const float* __restrict__ bih0,
                              const float* __restrict__ bhh0,
                              float* __restrict__ h0out) {
    __shared__ float slx[21], sly[21], srx[21], sry[21];
    __shared__ float sxb[IN];

    int out0 = blockIdx.x * 4;
    int b = out0 >> 10;

    int t = threadIdx.x;
    if (t < 21) {
        slx[t] = x[(91 + t) * 2 + 0];
        sly[t] = x[(91 + t) * 2 + 1];
        srx[t] = x[(112 + t) * 2 + 0];
        sry[t] = x[(112 + t) * 2 + 1];
    }
    __syncthreads();

    if (t < 21) {
        float lx_min = slx[0], lx_max = slx[0], ly_min = sly[0], ly_max = sly[0];
        float rx_min = srx[0], rx_max = srx[0], ry_min = sry[0], ry_max = sry[0];
        #pragma unroll
        for (int i = 1; i < 21; ++i) {
            lx_min = fminf(lx_min, slx[i]); lx_max = fmaxf(lx_max, slx[i]);
            ly_min = fminf(ly_min, sly[i]); ly_max = fmaxf(ly_max, sly[i]);
            rx_min = fminf(rx_min, srx[i]); rx_max = fmaxf(rx_max, srx[i]);
            ry_min = fminf(ry_min, sry[i]); ry_max = fmaxf(ry_max, sry[i]);
        }
        float w_l = lx_max - lx_min, h_l = ly_max - ly_min;
        float w_r = rx_max - rx_min, h_r = ry_max - ry_min;
        float w_b = x[5 * 2 + 0] - x[6 * 2 + 0];
        float h_b = 4.0f * w_b;
        float sbx = x[0], sby = x[1];
        float slx0 = slx[9], sly0 = sly[9];
        float srx0 = srx[9], sry0 = sry[9];
        bool cond_l = (w_l != 0.0f) && (h_l != 0.0f);
        bool cond_r = (w_r != 0.0f) && (h_r != 0.0f);
        bool cond_b = (w_b != 0.0f) && (h_b != 0.0f);
        float dlx = cond_l ? w_l : 1.0f, dly = cond_l ? h_l : 1.0f;
        float drx = cond_r ? w_r : 1.0f, dry = cond_r ? h_r : 1.0f;
        float wb  = cond_b ? w_b : 1.0f, hb  = cond_b ? h_b : 1.0f;

        float lx = slx[t], ly = sly[t], rx = srx[t], ry = sry[t];
        float vx, vy;
        switch (b) {
            case 0: vx = (lx - slx0) / dlx; vy = (ly - sly0) / dly; break;
            case 1: vx = (rx - srx0) / drx; vy = (ry - sry0) / dry; break;
            case 2: vx = (lx - sbx) / wb;   vy = (ly - sby);        break;
            case 3: vx = (rx - sbx);        vy = (ry - sby) / hb;   break;
            default:vx = (lx - rx) / wb;    vy = (ly - ry) / hb;    break;
        }
        sxb[2 * t + 0] = vx;
        sxb[2 * t + 1] = vy;
    }
    __syncthreads();

    int wave = t >> 6;
    int lane = t & 63;
    int j = (out0 + wave) & (H - 1);

    float xv = (lane < IN) ? sxb[lane] : 0.0f;
    const float* Wb = wih0 + (size_t)b * 4 * H * IN;
    float gi = 0.0f, gg = 0.0f, go = 0.0f;
    if (lane < IN) {
        gi = Wb[(size_t)(j)         * IN + lane] * xv;
        gg = Wb[(size_t)(j + 2 * H) * IN + lane] * xv;
        go = Wb[(size_t)(j + 3 * H) * IN + lane] * xv;
    }
    gi = wave_reduce_sum(gi);
    gg = wave_reduce_sum(gg);
    go = wave_reduce_sum(go);
    if (lane == 0) {
        size_t base = (size_t)b * 4 * H;
        gi += bih0[base + j]         + bhh0[base + j];
        gg += bih0[base + j + 2 * H] + bhh0[base + j + 2 * H];
        go += bih0[base + j + 3 * H] + bhh0[base + j + 3 * H];
        float c2 = sigmoidf_(gi) * tanhf(gg);
        h0out[b * H + j] = sigmoidf_(go) * tanhf(c2);
    }
}

__global__ void layer1_kernel(const float* __restrict__ wih1,
                              const float* __restrict__ bih1,
                              const float* __restrict__ bhh1,
                              const float* __restrict__ h0,
                              float* __restrict__ ctx) {
    __shared__ float4 hs[H / 4];
    int out0 = blockIdx.x * 8;
    int b = out0 >> 10;
    if (threadIdx.x < H / 4)
        hs[threadIdx.x] = ((const float4*)(h0 + b * H))[threadIdx.x];
    __syncthreads();

    int wave = threadIdx.x >> 6;
    int lane = threadIdx.x & 63;
    int j = (out0 + wave) & (H - 1);

    const float* Wb = wih1 + (size_t)b * 4 * H * H;
    const float4* ri = (const float4*)(Wb + (size_t)(j)         * H);
    const float4* rg = (const float4*)(Wb + (size_t)(j + 2 * H) * H);
    const float4* ro = (const float4*)(Wb + (size_t)(j + 3 * H) * H);

    float gi = 0.0f, gg = 0.0f, go = 0.0f;
    #pragma unroll
    for (int k = lane; k < H / 4; k += 64) {
        float4 h = hs[k];
        float4 a = ri[k]; gi += a.x * h.x + a.y * h.y + a.z * h.z + a.w * h.w;
        float4 c = rg[k]; gg += c.x * h.x + c.y * h.y + c.z * h.z + c.w * h.w;
        float4 d = ro[k]; go += d.x * h.x + d.y * h.y + d.z * h.z + d.w * h.w;
    }
    gi = wave_reduce_sum(gi);
    gg = wave_reduce_sum(gg);
    go = wave_reduce_sum(go);
    if (lane == 0) {
        size_t base = (size_t)b * 4 * H;
        gi += bih1[base + j]         + bhh1[base + j];
        gg += bih1[base + j + 2 * H] + bhh1[base + j + 2 * H];
        go += bih1[base + j + 3 * H] + bhh1[base + j + 3 * H];
        float c2 = sigmoidf_(gi) * tanhf(gg);
        ctx[b * H + j] = sigmoidf_(go) * tanhf(c2);
    }
}

__global__ void fuse_kernel(const float* __restrict__ fuse_w,
                            const float* __restrict__ fuse_b,
                            const float* __restrict__ ctx,
                            float* __restrict__ fused) {
    int row = blockIdx.x;
    const float4* r  = (const float4*)(fuse_w + (size_t)row * (NB * H));
    const float4* c4 = (const float4*)ctx;
    float acc = 0.0f;
    #pragma unroll
    for (int k = threadIdx.x; k < (NB * H) / 4; k += 256) {
        float4 a = r[k], c = c4[k];
        acc += a.x * c.x + a.y * c.y + a.z * c.z + a.w * c.w;
    }
    acc = wave_reduce_sum(acc);
    __shared__ float red[4];
    int wave = threadIdx.x >> 6, lane = threadIdx.x & 63;
    if (lane == 0) red[wave] = acc;
    __syncthreads();
    if (threadIdx.x == 0) {
        fused[row] = red[0] + red[1] + red[2] + red[3] + fuse_b[row];
    }
}

__global__ void fc_kernel(const float* __restrict__ fc_w,
                          const float* __restrict__ fc_b,
                          const float* __restrict__ fused,
                          float* __restrict__ out) {
    __shared__ float4 fs[H / 4];
    fs[threadIdx.x] = ((const float4*)fused)[threadIdx.x];
    __syncthreads();
    int wave = threadIdx.x >> 6, lane = threadIdx.x & 63;
    int row = blockIdx.x * 4 + wave;
    const float4* r = (const float4*)(fc_w + (size_t)row * H);
    float acc = 0.0f;
    #pragma unroll
    for (int k = lane; k < H / 4; k += 64) {
        float4 a = r[k], f = fs[k];
        acc += a.x * f.x + a.y * f.y + a.z * f.z + a.w * f.w;
    }
    acc = wave_reduce_sum(acc);
    if (lane == 0) out[row] = acc + fc_b[row];
}

// ---------------------------------------------------------------------------
extern "C" void kernel_launch(void* const* d_in, const int* in_sizes, int n_in,
                              void* d_out, int out_size, void* d_ws, size_t ws_size,
                              hipStream_t stream) {
    (void)in_sizes; (void)n_in; (void)out_size; (void)ws_size;
    const float* x      = (const float*)d_in[0];
    const float* W_ih0  = (const float*)d_in[1];
    // d_in[2] = W_hh0  : unused (h=0 at t=0)
    const float* b_ih0  = (const float*)d_in[3];
    const float* b_hh0  = (const float*)d_in[4];
    const float* W_ih1  = (const float*)d_in[5];
    // d_in[6] = W_hh1  : unused (h=0 at t=0)
    const float* b_ih1  = (const float*)d_in[7];
    const float* b_hh1  = (const float*)d_in[8];
    // d_in[9..12] = Wa, ba, Ws, bs : unused (softmax over 1 element == 1)
    const float* fuse_w = (const float*)d_in[13];
    const float* fuse_b = (const float*)d_in[14];
    const float* fc_w   = (const float*)d_in[15];
    const float* fc_b   = (const float*)d_in[16];
    float* out = (float*)d_out;

    float* ws    = (float*)d_ws;
    float* h0    = ws;            // 5120 floats
    float* ctx   = ws + 5120;     // 5120 floats
    float* fused = ws + 10240;    // 1024 floats

    void* args[] = {
        (void*)&x, (void*)&W_ih0, (void*)&b_ih0, (void*)&b_hh0,
        (void*)&W_ih1, (void*)&b_ih1, (void*)&b_hh1,
        (void*)&fuse_w, (void*)&fuse_b, (void*)&fc_w, (void*)&fc_b,
        (void*)&h0, (void*)&ctx, (void*)&fused, (void*)&out
    };
    hipError_t rc = hipLaunchCooperativeKernel((const void*)mega_kernel,
                                               dim3(1024), dim3(256),
                                               args, 0, stream);
    if (rc != hipSuccess) {
        // Fallback: previous verified 4-kernel pipeline.
        layer0_kernel<<<1280, 256, 0, stream>>>(x, W_ih0, b_ih0, b_hh0, h0);
        layer1_kernel<<<640, 512, 0, stream>>>(W_ih1, b_ih1, b_hh1, h0, ctx);
        fuse_kernel<<<1024, 256, 0, stream>>>(fuse_w, fuse_b, ctx, fused);
        fc_kernel<<<250, 256, 0, stream>>>(fc_w, fc_b, fused, out);
    }
}

// Round 2
// 248.313 us; speedup vs baseline: 2.1604x; 2.1604x over previous
//
#include <hip/hip_runtime.h>
#include <math.h>

#define H 1024
#define NB 5
#define IN 42
#define C_OUT 1000

__device__ __forceinline__ float sigmoidf_(float x) {
    return 1.0f / (1.0f + expf(-x));
}

__device__ __forceinline__ float wave_reduce_sum(float v) {
    #pragma unroll
    for (int off = 32; off > 0; off >>= 1) v += __shfl_xor(v, off);
    return v;
}

// 32-lane reduce: valid when contributions live only in lanes 0..31
// (lane 0 ends with the sum of lanes 0..31 of its 32-lane half).
__device__ __forceinline__ float half_reduce_sum(float v) {
    #pragma unroll
    for (int off = 16; off > 0; off >>= 1) v += __shfl_xor(v, off);
    return v;
}

// ---------------------------------------------------------------------------
// Kernel 1: prep (fused, per-block recompute) + layer0 LSTM cell (h=c=0).
// Each block handles 4 consecutive outputs of h0 (same branch b).
// g = W_ih0[b] @ xb[b] + b_ih0[b] + b_hh0[b]; f-gate dead (c=0).
// h0 = sigmoid(o) * tanh( sigmoid(i) * tanh(g) )
// Weight loads widened to float2 (21 lanes x 8B = one 168B row per instr).
// ---------------------------------------------------------------------------
__global__ void layer0_kernel(const float* __restrict__ x,
                              const float* __restrict__ wih0,
                              const float* __restrict__ bih0,
                              const float* __restrict__ bhh0,
                              float* __restrict__ h0out) {
    __shared__ float slx[21], sly[21], srx[21], sry[21];
    __shared__ float sxb[IN];

    int out0 = blockIdx.x * 4;
    int b = out0 >> 10;           // branch, uniform per block

    int t = threadIdx.x;
    if (t < 21) {
        slx[t] = x[(91 + t) * 2 + 0];
        sly[t] = x[(91 + t) * 2 + 1];
        srx[t] = x[(112 + t) * 2 + 0];
        sry[t] = x[(112 + t) * 2 + 1];
    }
    __syncthreads();

    if (t < 21) {
        float lx_min = slx[0], lx_max = slx[0], ly_min = sly[0], ly_max = sly[0];
        float rx_min = srx[0], rx_max = srx[0], ry_min = sry[0], ry_max = sry[0];
        #pragma unroll
        for (int i = 1; i < 21; ++i) {
            lx_min = fminf(lx_min, slx[i]); lx_max = fmaxf(lx_max, slx[i]);
            ly_min = fminf(ly_min, sly[i]); ly_max = fmaxf(ly_max, sly[i]);
            rx_min = fminf(rx_min, srx[i]); rx_max = fmaxf(rx_max, srx[i]);
            ry_min = fminf(ry_min, sry[i]); ry_max = fmaxf(ry_max, sry[i]);
        }
        float w_l = lx_max - lx_min, h_l = ly_max - ly_min;
        float w_r = rx_max - rx_min, h_r = ry_max - ry_min;
        float w_b = x[5 * 2 + 0] - x[6 * 2 + 0];
        float h_b = 4.0f * w_b;
        float sbx = x[0], sby = x[1];
        float slx0 = slx[9], sly0 = sly[9];
        float srx0 = srx[9], sry0 = sry[9];
        bool cond_l = (w_l != 0.0f) && (h_l != 0.0f);
        bool cond_r = (w_r != 0.0f) && (h_r != 0.0f);
        bool cond_b = (w_b != 0.0f) && (h_b != 0.0f);
        float dlx = cond_l ? w_l : 1.0f, dly = cond_l ? h_l : 1.0f;
        float drx = cond_r ? w_r : 1.0f, dry = cond_r ? h_r : 1.0f;
        float wb  = cond_b ? w_b : 1.0f, hb  = cond_b ? h_b : 1.0f;

        float lx = slx[t], ly = sly[t], rx = srx[t], ry = sry[t];
        float vx, vy;
        switch (b) {
            case 0: vx = (lx - slx0) / dlx; vy = (ly - sly0) / dly; break;
            case 1: vx = (rx - srx0) / drx; vy = (ry - sry0) / dry; break;
            case 2: vx = (lx - sbx) / wb;   vy = (ly - sby);        break;
            case 3: vx = (rx - sbx);        vy = (ry - sby) / hb;   break;
            default:vx = (lx - rx) / wb;    vy = (ly - ry) / hb;    break;
        }
        sxb[2 * t + 0] = vx;
        sxb[2 * t + 1] = vy;
    }
    __syncthreads();

    int wave = t >> 6;
    int lane = t & 63;
    int j = (out0 + wave) & (H - 1);

    const float* Wb = wih0 + (size_t)b * 4 * H * IN;
    float gi = 0.0f, gg = 0.0f, go = 0.0f;
    if (lane < 21) {
        // float2 loads: rows are 168B (8B-aligned since 168 % 8 == 0)
        const float2* ri = (const float2*)(Wb + (size_t)(j)         * IN);
        const float2* rg = (const float2*)(Wb + (size_t)(j + 2 * H) * IN);
        const float2* ro = (const float2*)(Wb + (size_t)(j + 3 * H) * IN);
        float2 xv = ((const float2*)sxb)[lane];
        float2 a = ri[lane]; gi = a.x * xv.x + a.y * xv.y;
        float2 c = rg[lane]; gg = c.x * xv.x + c.y * xv.y;
        float2 d = ro[lane]; go = d.x * xv.x + d.y * xv.y;
    }
    gi = half_reduce_sum(gi);
    gg = half_reduce_sum(gg);
    go = half_reduce_sum(go);
    if (lane == 0) {
        size_t base = (size_t)b * 4 * H;
        gi += bih0[base + j]         + bhh0[base + j];
        gg += bih0[base + j + 2 * H] + bhh0[base + j + 2 * H];
        go += bih0[base + j + 3 * H] + bhh0[base + j + 3 * H];
        float c2 = sigmoidf_(gi) * tanhf(gg);
        h0out[b * H + j] = sigmoidf_(go) * tanhf(c2);
    }
}

// ---------------------------------------------------------------------------
// Kernel 2: layer1 LSTM cell (h=c=0): one wave per output, 8 outputs/block
// (512 threads). h0[b] staged in LDS. ctx = h1 (softmax over 1 elem == 1).
// ---------------------------------------------------------------------------
__global__ void layer1_kernel(const float* __restrict__ wih1,
                              const float* __restrict__ bih1,
                              const float* __restrict__ bhh1,
                              const float* __restrict__ h0,
                              float* __restrict__ ctx) {
    __shared__ float4 hs[H / 4];  // 1024 floats
    int out0 = blockIdx.x * 8;            // first output of this block
    int b = out0 >> 10;                   // uniform per block (1024 % 8 == 0)
    if (threadIdx.x < H / 4)
        hs[threadIdx.x] = ((const float4*)(h0 + b * H))[threadIdx.x];
    __syncthreads();

    int wave = threadIdx.x >> 6;
    int lane = threadIdx.x & 63;
    int j = (out0 + wave) & (H - 1);

    const float* Wb = wih1 + (size_t)b * 4 * H * H;
    const float4* ri = (const float4*)(Wb + (size_t)(j)         * H);
    const float4* rg = (const float4*)(Wb + (size_t)(j + 2 * H) * H);
    const float4* ro = (const float4*)(Wb + (size_t)(j + 3 * H) * H);

    float gi = 0.0f, gg = 0.0f, go = 0.0f;
    #pragma unroll
    for (int k = lane; k < H / 4; k += 64) {
        float4 h = hs[k];
        float4 a = ri[k]; gi += a.x * h.x + a.y * h.y + a.z * h.z + a.w * h.w;
        float4 c = rg[k]; gg += c.x * h.x + c.y * h.y + c.z * h.z + c.w * h.w;
        float4 d = ro[k]; go += d.x * h.x + d.y * h.y + d.z * h.z + d.w * h.w;
    }
    gi = wave_reduce_sum(gi);
    gg = wave_reduce_sum(gg);
    go = wave_reduce_sum(go);
    if (lane == 0) {
        size_t base = (size_t)b * 4 * H;
        gi += bih1[base + j]         + bhh1[base + j];
        gg += bih1[base + j + 2 * H] + bhh1[base + j + 2 * H];
        go += bih1[base + j + 3 * H] + bhh1[base + j + 3 * H];
        float c2 = sigmoidf_(gi) * tanhf(gg);
        ctx[b * H + j] = sigmoidf_(go) * tanhf(c2);
    }
}

// ---------------------------------------------------------------------------
// Kernel 3: fused = fuse_w @ ctx_flat + fuse_b   (1024 x 5120 matvec)
// one block (256 threads) per output row
// ---------------------------------------------------------------------------
__global__ void fuse_kernel(const float* __restrict__ fuse_w,
                            const float* __restrict__ fuse_b,
                            const float* __restrict__ ctx,
                            float* __restrict__ fused) {
    int row = blockIdx.x;
    const float4* r  = (const float4*)(fuse_w + (size_t)row * (NB * H));
    const float4* c4 = (const float4*)ctx;
    float acc = 0.0f;
    #pragma unroll
    for (int k = threadIdx.x; k < (NB * H) / 4; k += 256) {  // 5 iters
        float4 a = r[k], c = c4[k];
        acc += a.x * c.x + a.y * c.y + a.z * c.z + a.w * c.w;
    }
    acc = wave_reduce_sum(acc);
    __shared__ float red[4];
    int wave = threadIdx.x >> 6, lane = threadIdx.x & 63;
    if (lane == 0) red[wave] = acc;
    __syncthreads();
    if (threadIdx.x == 0) {
        fused[row] = red[0] + red[1] + red[2] + red[3] + fuse_b[row];
    }
}

// ---------------------------------------------------------------------------
// Kernel 4: logits = fc_w @ fused + fc_b   (1000 x 1024 matvec)
// one wave per output row, 4 rows/block, fused staged in LDS
// ---------------------------------------------------------------------------
__global__ void fc_kernel(const float* __restrict__ fc_w,
                          const float* __restrict__ fc_b,
                          const float* __restrict__ fused,
                          float* __restrict__ out) {
    __shared__ float4 fs[H / 4];
    fs[threadIdx.x] = ((const float4*)fused)[threadIdx.x];
    __syncthreads();
    int wave = threadIdx.x >> 6, lane = threadIdx.x & 63;
    int row = blockIdx.x * 4 + wave;  // 250 blocks * 4 = 1000 exactly
    const float4* r = (const float4*)(fc_w + (size_t)row * H);
    float acc = 0.0f;
    #pragma unroll
    for (int k = lane; k < H / 4; k += 64) {
        float4 a = r[k], f = fs[k];
        acc += a.x * f.x + a.y * f.y + a.z * f.z + a.w * f.w;
    }
    acc = wave_reduce_sum(acc);
    if (lane == 0) out[row] = acc + fc_b[row];
}

// ---------------------------------------------------------------------------
extern "C" void kernel_launch(void* const* d_in, const int* in_sizes, int n_in,
                              void* d_out, int out_size, void* d_ws, size_t ws_size,
                              hipStream_t stream) {
    (void)in_sizes; (void)n_in; (void)out_size; (void)ws_size;
    const float* x      = (const float*)d_in[0];
    const float* W_ih0  = (const float*)d_in[1];
    // d_in[2] = W_hh0  : unused (h=0 at t=0)
    const float* b_ih0  = (const float*)d_in[3];
    const float* b_hh0  = (const float*)d_in[4];
    const float* W_ih1  = (const float*)d_in[5];
    // d_in[6] = W_hh1  : unused (h=0 at t=0)
    const float* b_ih1  = (const float*)d_in[7];
    const float* b_hh1  = (const float*)d_in[8];
    // d_in[9..12] = Wa, ba, Ws, bs : unused (softmax over 1 element == 1)
    const float* fuse_w = (const float*)d_in[13];
    const float* fuse_b = (const float*)d_in[14];
    const float* fc_w   = (const float*)d_in[15];
    const float* fc_b   = (const float*)d_in[16];
    float* out = (float*)d_out;

    float* ws    = (float*)d_ws;
    float* h0    = ws;            // 5120 floats
    float* ctx   = ws + 5120;     // 5120 floats
    float* fused = ws + 10240;    // 1024 floats

    layer0_kernel<<<1280, 256, 0, stream>>>(x, W_ih0, b_ih0, b_hh0, h0);
    layer1_kernel<<<640, 512, 0, stream>>>(W_ih1, b_ih1, b_hh1, h0, ctx);
    fuse_kernel<<<1024, 256, 0, stream>>>(fuse_w, fuse_b, ctx, fused);
    fc_kernel<<<250, 256, 0, stream>>>(fc_w, fc_b, fused, out);
}